// Round 6
// baseline (358.928 us; speedup 1.0000x reference)
//
#include <hip/hip_runtime.h>
#include <hip/hip_bf16.h>
#include <math.h>

// GATEncoder round 6.
// - gemm_att: W staged in TWO 64-row halves (32KB LDS + 2KB red) -> 4 blocks/CU
//   (round 5: 66KB -> 2 blocks/CU -> 13.7% occupancy, latency-bound at 19% VALU).
// - CSR: scan_tops deleted (scan_add self-computes its base via 64-lane
//   butterfly over block partials); cur zeroing folded into scan_add.
// - gat_gather4 unchanged (isolate deltas).

#define NEG_SLOPE 0.2f

// ---------------- CSR build ----------------
__global__ void deg_hist(const int* __restrict__ ei, int* __restrict__ deg, int E) {
    int e = blockIdx.x * blockDim.x + threadIdx.x;
    if (e < E) atomicAdd(&deg[ei[E + e]], 1);
}

// per-1024-chunk sums of (deg[i]+1)  [+1 = self loop]
__global__ __launch_bounds__(256) void scan_part(const int* __restrict__ deg,
                                                 int* __restrict__ bsum, int n) {
    const int t = threadIdx.x;
    const int i0 = blockIdx.x * 1024 + t * 4;
    int s = 0;
#pragma unroll
    for (int k = 0; k < 4; ++k) { int i = i0 + k; if (i < n) s += deg[i] + 1; }
#pragma unroll
    for (int o = 1; o < 64; o <<= 1) s += __shfl_xor(s, o, 64);
    __shared__ int ws[4];
    if ((t & 63) == 0) ws[t >> 6] = s;
    __syncthreads();
    if (t == 0) bsum[blockIdx.x] = ws[0] + ws[1] + ws[2] + ws[3];
}

// offs[] from deg[] + bsum[]; each block derives its own base (butterfly over
// partials of preceding blocks). Also zeroes cur[] and writes offs[n].
__global__ __launch_bounds__(256) void scan_add(const int* __restrict__ deg,
                                                const int* __restrict__ bsum,
                                                int* __restrict__ offs,
                                                int* __restrict__ cur, int n) {
    __shared__ int sbase;
    const int t = threadIdx.x;
    if (t < 64) {
        int v = (t < (int)blockIdx.x) ? bsum[t] : 0;  // blockIdx.x <= 63
#pragma unroll
        for (int o = 1; o < 64; o <<= 1) v += __shfl_xor(v, o, 64);
        if (t == 0) sbase = v;
    }
    __syncthreads();
    const int i0 = blockIdx.x * 1024 + t * 4;
    int loc[4];
    int s = 0;
#pragma unroll
    for (int k = 0; k < 4; ++k) { int i = i0 + k; loc[k] = (i < n) ? deg[i] + 1 : 0; s += loc[k]; }
    int incl = s;
#pragma unroll
    for (int o = 1; o < 64; o <<= 1) {
        int u = __shfl_up(incl, o, 64);
        if ((t & 63) >= o) incl += u;
    }
    __shared__ int wsum[4];
    const int w = t >> 6;
    if ((t & 63) == 63) wsum[w] = incl;
    __syncthreads();
    int wbase = 0;
#pragma unroll
    for (int k = 0; k < 4; ++k) if (k < w) wbase += wsum[k];
    int base = sbase + wbase + (incl - s);
#pragma unroll
    for (int k = 0; k < 4; ++k) {
        int i = i0 + k;
        if (i < n) { offs[i] = base; cur[i] = 0; }
        base += loc[k];
        if (i == n - 1) offs[n] = base;
    }
}

__global__ void scatter_edges(const int* __restrict__ ei, const int* __restrict__ offs,
                              int* __restrict__ cur, int* __restrict__ csr, int E, int ET) {
    int e = blockIdx.x * blockDim.x + threadIdx.x;
    if (e >= ET) return;
    int s, d;
    if (e < E) { s = ei[e]; d = ei[E + e]; } else { s = d = e - E; }
    int pos = atomicAdd(&cur[d], 1);
    csr[offs[d] + pos] = s;
}

// ---------------- GEMM + fused attention logits ----------------
// block: 64 rows x 128 cols; thread (rg=tid>>4, cg=tid&15): 4 rows x
// cols [cg*4, cg*4+4) u [64+cg*4, 64+cg*4+4).
// W staged in LDS in TWO 64-k-row halves (32KB) -> 4 blocks/CU.
#define GETK(v, kk) ((kk) == 0 ? (v).x : (kk) == 1 ? (v).y : (kk) == 2 ? (v).z : (v).w)

__device__ inline unsigned short f2bf(float x) {
    union { float f; unsigned int u; } v; v.f = x;
    unsigned int b = v.u + 0x7fffu + ((v.u >> 16) & 1u);  // round-nearest-even
    return (unsigned short)(b >> 16);
}
__device__ inline unsigned int pack2bf(float a, float b) {
    return (unsigned int)f2bf(a) | ((unsigned int)f2bf(b) << 16);
}

template <int H>
__global__ __launch_bounds__(256) void gemm_att(const float* __restrict__ X,
                                                const float* __restrict__ W,
                                                unsigned int* __restrict__ Yb,
                                                const float* __restrict__ att_s,
                                                const float* __restrict__ att_d,
                                                float* __restrict__ as_,
                                                float* __restrict__ ad_, int n) {
    __shared__ float Ws[64 * 128];
    __shared__ float red[64][H][2];
    {
        float* rf = (float*)red;
        for (int i = threadIdx.x; i < 64 * H * 2; i += 256) rf[i] = 0.f;
    }
    const int cg = threadIdx.x & 15;
    const int rg = threadIdx.x >> 4;
    const int r0 = blockIdx.x * 64 + rg * 4;
    const int c0 = cg * 4, c1 = 64 + cg * 4;
    float acc[4][8] = {};
    const int nr = min(4, n - r0);  // may be <= 0; no early return (barriers!)

    const float4* x0 = (const float4*)(X + (size_t)(r0 + 0) * 128);
    const float4* x1 = (const float4*)(X + (size_t)(r0 + 1) * 128);
    const float4* x2 = (const float4*)(X + (size_t)(r0 + 2) * 128);
    const float4* x3 = (const float4*)(X + (size_t)(r0 + 3) * 128);

    for (int half = 0; half < 2; ++half) {
        if (half) __syncthreads();  // all waves done reading previous half
        {
            const float4* W4 = (const float4*)(W + half * 64 * 128);
            float4* S4 = (float4*)Ws;
#pragma unroll
            for (int i = 0; i < 8; ++i) S4[threadIdx.x + 256 * i] = W4[threadIdx.x + 256 * i];
        }
        __syncthreads();

        if (nr == 4) {
#pragma unroll 2
            for (int k4l = 0; k4l < 16; ++k4l) {
                const int k4 = half * 16 + k4l;
                float4 a0 = x0[k4], a1 = x1[k4], a2 = x2[k4], a3 = x3[k4];
#pragma unroll
                for (int kk = 0; kk < 4; ++kk) {
                    const float* wr = &Ws[(k4l * 4 + kk) * 128];
                    float4 w0 = *(const float4*)(wr + c0);
                    float4 w1 = *(const float4*)(wr + c1);
                    float v;
                    v = GETK(a0, kk);
                    acc[0][0] = fmaf(v, w0.x, acc[0][0]); acc[0][1] = fmaf(v, w0.y, acc[0][1]);
                    acc[0][2] = fmaf(v, w0.z, acc[0][2]); acc[0][3] = fmaf(v, w0.w, acc[0][3]);
                    acc[0][4] = fmaf(v, w1.x, acc[0][4]); acc[0][5] = fmaf(v, w1.y, acc[0][5]);
                    acc[0][6] = fmaf(v, w1.z, acc[0][6]); acc[0][7] = fmaf(v, w1.w, acc[0][7]);
                    v = GETK(a1, kk);
                    acc[1][0] = fmaf(v, w0.x, acc[1][0]); acc[1][1] = fmaf(v, w0.y, acc[1][1]);
                    acc[1][2] = fmaf(v, w0.z, acc[1][2]); acc[1][3] = fmaf(v, w0.w, acc[1][3]);
                    acc[1][4] = fmaf(v, w1.x, acc[1][4]); acc[1][5] = fmaf(v, w1.y, acc[1][5]);
                    acc[1][6] = fmaf(v, w1.z, acc[1][6]); acc[1][7] = fmaf(v, w1.w, acc[1][7]);
                    v = GETK(a2, kk);
                    acc[2][0] = fmaf(v, w0.x, acc[2][0]); acc[2][1] = fmaf(v, w0.y, acc[2][1]);
                    acc[2][2] = fmaf(v, w0.z, acc[2][2]); acc[2][3] = fmaf(v, w0.w, acc[2][3]);
                    acc[2][4] = fmaf(v, w1.x, acc[2][4]); acc[2][5] = fmaf(v, w1.y, acc[2][5]);
                    acc[2][6] = fmaf(v, w1.z, acc[2][6]); acc[2][7] = fmaf(v, w1.w, acc[2][7]);
                    v = GETK(a3, kk);
                    acc[3][0] = fmaf(v, w0.x, acc[3][0]); acc[3][1] = fmaf(v, w0.y, acc[3][1]);
                    acc[3][2] = fmaf(v, w0.z, acc[3][2]); acc[3][3] = fmaf(v, w0.w, acc[3][3]);
                    acc[3][4] = fmaf(v, w1.x, acc[3][4]); acc[3][5] = fmaf(v, w1.y, acc[3][5]);
                    acc[3][6] = fmaf(v, w1.z, acc[3][6]); acc[3][7] = fmaf(v, w1.w, acc[3][7]);
                }
            }
        } else if (nr > 0) {
            for (int kl = 0; kl < 64; ++kl) {
                const int k = half * 64 + kl;
                const float* wr = &Ws[kl * 128];
                for (int r = 0; r < nr; ++r) {
                    float v = X[(size_t)(r0 + r) * 128 + k];
#pragma unroll
                    for (int c = 0; c < 4; ++c) {
                        acc[r][c]     = fmaf(v, wr[c0 + c], acc[r][c]);
                        acc[r][4 + c] = fmaf(v, wr[c1 + c], acc[r][4 + c]);
                    }
                }
            }
        }
    }

    if (nr > 0) {
        const float4 sv0 = *(const float4*)(att_s + c0);
        const float4 dv0 = *(const float4*)(att_d + c0);
        const float4 sv1 = *(const float4*)(att_s + c1);
        const float4 dv1 = *(const float4*)(att_d + c1);
        for (int r = 0; r < nr; ++r) {
            unsigned int* br = Yb + (size_t)(r0 + r) * 64;
            uint2 p0 = {pack2bf(acc[r][0], acc[r][1]), pack2bf(acc[r][2], acc[r][3])};
            uint2 p1 = {pack2bf(acc[r][4], acc[r][5]), pack2bf(acc[r][6], acc[r][7])};
            *(uint2*)(br + cg * 2) = p0;
            *(uint2*)(br + 32 + cg * 2) = p1;
            float ps0 = acc[r][0] * sv0.x + acc[r][1] * sv0.y + acc[r][2] * sv0.z + acc[r][3] * sv0.w;
            float pd0 = acc[r][0] * dv0.x + acc[r][1] * dv0.y + acc[r][2] * dv0.z + acc[r][3] * dv0.w;
            float ps1 = acc[r][4] * sv1.x + acc[r][5] * sv1.y + acc[r][6] * sv1.z + acc[r][7] * sv1.w;
            float pd1 = acc[r][4] * dv1.x + acc[r][5] * dv1.y + acc[r][6] * dv1.z + acc[r][7] * dv1.w;
            const int rl = rg * 4 + r;
            if constexpr (H == 4) {
                atomicAdd(&red[rl][c0 >> 5][0], ps0); atomicAdd(&red[rl][c0 >> 5][1], pd0);
                atomicAdd(&red[rl][c1 >> 5][0], ps1); atomicAdd(&red[rl][c1 >> 5][1], pd1);
            } else {
                atomicAdd(&red[rl][0][0], ps0 + ps1); atomicAdd(&red[rl][0][1], pd0 + pd1);
            }
        }
    }
    __syncthreads();
    for (int i = threadIdx.x; i < 64 * H; i += 256) {
        const int rl = i / H, h = i - rl * H;
        const int node = blockIdx.x * 64 + rl;
        if (node < n) {
            as_[(size_t)node * H + h] = red[rl][h][0];
            ad_[(size_t)node * H + h] = red[rl][h][1];
        }
    }
}

// ---------------- gather v4: lane-parallel softmax, broadcast inner loop ----
template <int H, bool DO_ELU>
__global__ __launch_bounds__(256) void gat_gather4(
    const int* __restrict__ csr, const int* __restrict__ offs,
    const float* __restrict__ as_, const float* __restrict__ ad_,
    const unsigned int* __restrict__ hb,  // bf16x2 rows, 64 uints/node
    const float* __restrict__ bias, float* __restrict__ out, int n)
{
    constexpr int PW = (H == 4) ? 8 : 2;  // LDS words per edge {p[H], s}
    __shared__ float plds[4][64][PW];
    const int node = (int)(((size_t)blockIdx.x * blockDim.x + threadIdx.x) >> 6);
    if (node >= n) return;  // whole waves exit; kernel has no block barriers
    const int lane = threadIdx.x & 63;
    const int w = threadIdx.x >> 6;
    const int hd = lane >> 4;
    const int start = offs[node];
    const int deg = offs[node + 1] - start;  // >= 1 (self-loop)

    float adx = 0.f, ady = 0.f, adz = 0.f, adw = 0.f;
    if constexpr (H == 4) {
        const float4 adv = *(const float4*)(ad_ + (size_t)node * 4);
        adx = adv.x; ady = adv.y; adz = adv.z; adw = adv.w;
    } else {
        adx = ad_[node];
    }

    float2 acc = {0.f, 0.f};
    float dsx = 0.f, dsy = 0.f, dsz = 0.f, dsw = 0.f;

    for (int base = 0; base < deg; base += 64) {
        const int cnt = min(deg - base, 64);
        if (lane < cnt) {
            const int s = csr[start + base + lane];
            const float sf = __int_as_float(s);
            if constexpr (H == 4) {
                const float4 a = ((const float4*)as_)[s];
                float e0 = a.x + adx; e0 = fmaxf(e0, NEG_SLOPE * e0);
                float e1 = a.y + ady; e1 = fmaxf(e1, NEG_SLOPE * e1);
                float e2 = a.z + adz; e2 = fmaxf(e2, NEG_SLOPE * e2);
                float e3 = a.w + adw; e3 = fmaxf(e3, NEG_SLOPE * e3);
                float4 p4 = {__expf(e0), __expf(e1), __expf(e2), __expf(e3)};
                dsx += p4.x; dsy += p4.y; dsz += p4.z; dsw += p4.w;
                *(float4*)&plds[w][lane][0] = p4;
                float4 s4 = {sf, sf, sf, sf};
                *(float4*)&plds[w][lane][4] = s4;
            } else {
                float e0 = as_[s] + adx; e0 = fmaxf(e0, NEG_SLOPE * e0);
                float p = __expf(e0);
                dsx += p;
                float2 ps = {p, sf};
                *(float2*)&plds[w][lane][0] = ps;
            }
        }
        asm volatile("s_waitcnt lgkmcnt(0)" ::: "memory");
        __builtin_amdgcn_sched_barrier(0);

        float pA = 0.f, pB = 0.f, pC = 0.f;
        unsigned int hA = 0, hB = 0, hC = 0;
#define PRELB(S, T)                                                             \
    if ((T) < cnt) {                                                            \
        const float* q = &plds[w][(T)][0];                                      \
        int _s;                                                                 \
        if constexpr (H == 4) { p##S = q[hd]; _s = __float_as_int(q[4 + hd]); } \
        else                  { p##S = q[0];  _s = __float_as_int(q[1]); }      \
        h##S = hb[(size_t)(unsigned)_s * 64 + lane];                            \
    }
#define CONSB(S)                                                                \
    {                                                                           \
        acc.x = fmaf(p##S, __uint_as_float(h##S << 16), acc.x);                 \
        acc.y = fmaf(p##S, __uint_as_float(h##S & 0xffff0000u), acc.y);         \
    }
        PRELB(A, 0)
        PRELB(B, 1)
        PRELB(C, 2)
        int t = 0;
        for (; t + 3 <= cnt; t += 3) {
            CONSB(A) PRELB(A, t + 3)
            CONSB(B) PRELB(B, t + 4)
            CONSB(C) PRELB(C, t + 5)
        }
        if (t < cnt)     CONSB(A)
        if (t + 1 < cnt) CONSB(B)
        if (t + 2 < cnt) CONSB(C)
#undef PRELB
#undef CONSB
    }

#pragma unroll
    for (int o = 1; o < 64; o <<= 1) {
        dsx += __shfl_xor(dsx, o, 64);
        if constexpr (H == 4) {
            dsy += __shfl_xor(dsy, o, 64);
            dsz += __shfl_xor(dsz, o, 64);
            dsw += __shfl_xor(dsw, o, 64);
        }
    }
    float ds;
    if constexpr (H == 4) ds = hd == 0 ? dsx : hd == 1 ? dsy : hd == 2 ? dsz : dsw;
    else                  ds = dsx;

    const float2 bv = ((const float2*)bias)[lane];
    const float inv = 1.f / (ds + 1e-16f);
    float v0 = acc.x * inv + bv.x;
    float v1 = acc.y * inv + bv.y;
    if constexpr (DO_ELU) {
        v0 = v0 > 0.f ? v0 : __expf(v0) - 1.f;
        v1 = v1 > 0.f ? v1 : __expf(v1) - 1.f;
    }
    ((float2*)out)[(size_t)node * 64 + lane] = {v0, v1};
}

extern "C" void kernel_launch(void* const* d_in, const int* in_sizes, int n_in,
                              void* d_out, int out_size, void* d_ws, size_t ws_size,
                              hipStream_t stream) {
    const float* x        = (const float*)d_in[0];
    const int*   ei       = (const int*)d_in[1];
    const float* W1       = (const float*)d_in[2];
    const float* att_src1 = (const float*)d_in[3];
    const float* att_dst1 = (const float*)d_in[4];
    const float* b1       = (const float*)d_in[5];
    const float* W2       = (const float*)d_in[6];
    const float* att_src2 = (const float*)d_in[7];
    const float* att_dst2 = (const float*)d_in[8];
    const float* b2       = (const float*)d_in[9];

    const int n  = in_sizes[0] / 128;
    const int E  = in_sizes[1] / 2;
    const int ET = E + n;
    const int nb = (n + 1023) / 1024;  // <= 64 for n <= 65536

    float*        ws   = (float*)d_ws;
    float*        B    = ws;                                   // [n*128] layer-1 out
    unsigned int* Hbf  = (unsigned int*)(B + (size_t)n * 128); // [n*64] bf16 h
    float*        as_  = (float*)(Hbf + (size_t)n * 64);       // [n*4]
    float*        ad_  = as_ + (size_t)n * 4;                  // [n*4]
    int*          deg  = (int*)(ad_ + (size_t)n * 4);          // [n]
    int*          cur  = deg + n;                              // [n]
    int*          offs = cur + n;                              // [n+1]
    int*          bsum = offs + n + 1;                         // [64]
    int*          csr  = bsum + 64;                            // [ET]

    float* outf = (float*)d_out;

    // ---------------- CSR build ----------------
    hipMemsetAsync(deg, 0, (size_t)n * sizeof(int), stream);
    deg_hist<<<(E + 255) / 256, 256, 0, stream>>>(ei, deg, E);
    scan_part<<<nb, 256, 0, stream>>>(deg, bsum, n);
    scan_add<<<nb, 256, 0, stream>>>(deg, bsum, offs, cur, n);
    scatter_edges<<<(ET + 255) / 256, 256, 0, stream>>>(ei, offs, cur, csr, E, ET);

    // ---------------- layer 1 ----------------
    gemm_att<4><<<(n + 63) / 64, 256, 0, stream>>>(x, W1, Hbf, att_src1, att_dst1, as_, ad_, n);
    gat_gather4<4, true><<<((size_t)n * 64 + 255) / 256, 256, 0, stream>>>(
        csr, offs, as_, ad_, Hbf, b1, B, n);

    // ---------------- layer 2 ----------------
    gemm_att<1><<<(n + 63) / 64, 256, 0, stream>>>(B, W2, Hbf, att_src2, att_dst2, as_, ad_, n);
    gat_gather4<1, false><<<((size_t)n * 64 + 255) / 256, 256, 0, stream>>>(
        csr, offs, as_, ad_, Hbf, b2, outf, n);
}

// Round 7
// 304.866 us; speedup vs baseline: 1.1773x; 1.1773x over previous
//
#include <hip/hip_runtime.h>
#include <hip/hip_bf16.h>
#include <math.h>

// GATEncoder round 7.
// - GEMM switched to MFMA bf16 (mfma_f32_16x16x32_bf16): f32 VALU gemm was
//   stuck at 59 us (latency-bound, grid-capped occupancy). X-tile + W^T staged
//   in XOR-swizzled LDS; output written in fragment-native permuted layout
//   (storage j = c*8 + cf <-> channel col = (j&7)*16 + (j>>3)) so the epilogue
//   is 4 coalesced dwordx4 stores per lane.
// - att logits de-fused back to a tiny bf16-reading kernel (round-5 fusion was
//   net negative).
// - gather4: only index-mapping changes (hd = lane&3; permuted bias/out cols).

#define NEG_SLOPE 0.2f

using bf16x8 = __attribute__((ext_vector_type(8))) short;
using f32x4  = __attribute__((ext_vector_type(4))) float;

__device__ inline unsigned short f2bf(float x) {
    union { float f; unsigned int u; } v; v.f = x;
    unsigned int b = v.u + 0x7fffu + ((v.u >> 16) & 1u);  // round-nearest-even
    return (unsigned short)(b >> 16);
}
__device__ inline unsigned int pack2bf(float a, float b) {
    return (unsigned int)f2bf(a) | ((unsigned int)f2bf(b) << 16);
}
__device__ inline float bf_lo(unsigned int u) { return __uint_as_float(u << 16); }
__device__ inline float bf_hi(unsigned int u) { return __uint_as_float(u & 0xffff0000u); }

// ---------------- CSR build (unchanged) ----------------
__global__ void deg_hist(const int* __restrict__ ei, int* __restrict__ deg, int E) {
    int e = blockIdx.x * blockDim.x + threadIdx.x;
    if (e < E) atomicAdd(&deg[ei[E + e]], 1);
}

__global__ __launch_bounds__(256) void scan_part(const int* __restrict__ deg,
                                                 int* __restrict__ bsum, int n) {
    const int t = threadIdx.x;
    const int i0 = blockIdx.x * 1024 + t * 4;
    int s = 0;
#pragma unroll
    for (int k = 0; k < 4; ++k) { int i = i0 + k; if (i < n) s += deg[i] + 1; }
#pragma unroll
    for (int o = 1; o < 64; o <<= 1) s += __shfl_xor(s, o, 64);
    __shared__ int ws[4];
    if ((t & 63) == 0) ws[t >> 6] = s;
    __syncthreads();
    if (t == 0) bsum[blockIdx.x] = ws[0] + ws[1] + ws[2] + ws[3];
}

__global__ __launch_bounds__(256) void scan_add(const int* __restrict__ deg,
                                                const int* __restrict__ bsum,
                                                int* __restrict__ offs,
                                                int* __restrict__ cur, int n) {
    __shared__ int sbase;
    const int t = threadIdx.x;
    if (t < 64) {
        int v = (t < (int)blockIdx.x) ? bsum[t] : 0;  // blockIdx.x <= 63
#pragma unroll
        for (int o = 1; o < 64; o <<= 1) v += __shfl_xor(v, o, 64);
        if (t == 0) sbase = v;
    }
    __syncthreads();
    const int i0 = blockIdx.x * 1024 + t * 4;
    int loc[4];
    int s = 0;
#pragma unroll
    for (int k = 0; k < 4; ++k) { int i = i0 + k; loc[k] = (i < n) ? deg[i] + 1 : 0; s += loc[k]; }
    int incl = s;
#pragma unroll
    for (int o = 1; o < 64; o <<= 1) {
        int u = __shfl_up(incl, o, 64);
        if ((t & 63) >= o) incl += u;
    }
    __shared__ int wsum[4];
    const int w = t >> 6;
    if ((t & 63) == 63) wsum[w] = incl;
    __syncthreads();
    int wbase = 0;
#pragma unroll
    for (int k = 0; k < 4; ++k) if (k < w) wbase += wsum[k];
    int base = sbase + wbase + (incl - s);
#pragma unroll
    for (int k = 0; k < 4; ++k) {
        int i = i0 + k;
        if (i < n) { offs[i] = base; cur[i] = 0; }
        base += loc[k];
        if (i == n - 1) offs[n] = base;
    }
}

__global__ void scatter_edges(const int* __restrict__ ei, const int* __restrict__ offs,
                              int* __restrict__ cur, int* __restrict__ csr, int E, int ET) {
    int e = blockIdx.x * blockDim.x + threadIdx.x;
    if (e >= ET) return;
    int s, d;
    if (e < E) { s = ei[e]; d = ei[E + e]; } else { s = d = e - E; }
    int pos = atomicAdd(&cur[d], 1);
    csr[offs[d] + pos] = s;
}

// ---------------- prep: W[k][c] f32 -> WT[c][k] bf16 (both layers) ----------
__global__ __launch_bounds__(256) void prep_w(const float* __restrict__ W1,
                                              const float* __restrict__ W2,
                                              unsigned short* __restrict__ WT1,
                                              unsigned short* __restrict__ WT2) {
    const float* W = blockIdx.x ? W2 : W1;
    unsigned short* WT = blockIdx.x ? WT2 : WT1;
    __shared__ float Wl[64][132];
    const int tid = threadIdx.x;
    for (int p = 0; p < 2; ++p) {
        if (p) __syncthreads();
        for (int u = tid; u < 2048; u += 256) {  // 64 rows x 32 float4
            int row = u >> 5, ch = u & 31;
            float4 v = *(const float4*)(W + (size_t)(p * 64 + row) * 128 + ch * 4);
            Wl[row][ch * 4 + 0] = v.x; Wl[row][ch * 4 + 1] = v.y;
            Wl[row][ch * 4 + 2] = v.z; Wl[row][ch * 4 + 3] = v.w;
        }
        __syncthreads();
        for (int u = tid; u < 2048; u += 256) {  // 128 c x 16 kc(4 k each)
            int c = u >> 4, kc = u & 15;
            uint2 o;
            o.x = pack2bf(Wl[kc * 4 + 0][c], Wl[kc * 4 + 1][c]);
            o.y = pack2bf(Wl[kc * 4 + 2][c], Wl[kc * 4 + 3][c]);
            *(uint2*)(WT + (size_t)c * 128 + p * 64 + kc * 4) = o;
        }
    }
}

// ---------------- convert x f32 -> bf16 ----------------
__global__ void f32_to_bf16(const float* __restrict__ in, uint4* __restrict__ out, int units) {
    int i = blockIdx.x * blockDim.x + threadIdx.x;
    if (i >= units) return;
    const float4* p = (const float4*)in + (size_t)i * 2;
    float4 a = p[0], b = p[1];
    uint4 o = {pack2bf(a.x, a.y), pack2bf(a.z, a.w), pack2bf(b.x, b.y), pack2bf(b.z, b.w)};
    out[i] = o;
}

// ---------------- MFMA GEMM: Yb[n][128]perm = Ab[n][128] @ W (via WT) -------
// block 256 thr = 4 waves, tile 64 rows x 128 cols, K=128 in one LDS stage.
// wave w: rows [w*16, w*16+16). A-frag: lane l -> row (l&15), k = (l>>4)*8+j.
// B-frag: lane l -> col cf*16+(l&15), same k. C: col = l&15, row = (l>>4)*4+r.
// LDS XOR-swizzle: byte_in_row ^= ((row&7)<<4)  (16-way -> 2-way = free).
// Output permuted: storage j = (l&15)*8 + cf  <->  channel col = cf*16+(l&15).
__global__ __launch_bounds__(256) void gemm_mfma(const unsigned short* __restrict__ Ab,
                                                 const unsigned short* __restrict__ WTb,
                                                 unsigned int* __restrict__ Yb, int n) {
    __shared__ unsigned short XL[64 * 128];
    __shared__ unsigned short WL[128 * 128];
    const int tid = threadIdx.x;
    const int r0g = blockIdx.x * 64;
#pragma unroll
    for (int p = 0; p < 4; ++p) {  // stage X tile (swizzled)
        int u = tid + 256 * p;     // 64 rows x 16 chunks
        int row = u >> 4, ch = u & 15;
        uint4 v = {0, 0, 0, 0};
        int gr = r0g + row;
        if (gr < n) v = *(const uint4*)(Ab + (size_t)gr * 128 + ch * 8);
        int byte = (ch * 16) ^ ((row & 7) << 4);
        *(uint4*)((char*)XL + row * 256 + byte) = v;
    }
#pragma unroll
    for (int p = 0; p < 8; ++p) {  // stage WT (swizzled)
        int u = tid + 256 * p;     // 128 c x 16 chunks
        int c = u >> 4, ch = u & 15;
        uint4 v = *(const uint4*)(WTb + (size_t)c * 128 + ch * 8);
        int byte = (ch * 16) ^ ((c & 7) << 4);
        *(uint4*)((char*)WL + c * 256 + byte) = v;
    }
    __syncthreads();

    const int w = tid >> 6, lane = tid & 63;
    const int lr = lane & 15, lq = lane >> 4;
    const int swz = (lr & 7) << 4;  // both A-row and B-col swizzle reduce to lr&7
    f32x4 acc[8];
#pragma unroll
    for (int cf = 0; cf < 8; ++cf) acc[cf] = (f32x4){0.f, 0.f, 0.f, 0.f};

    const char* XB = (const char*)XL + (w * 16 + lr) * 256;
    const char* WB = (const char*)WL + lr * 256;
#pragma unroll
    for (int k4 = 0; k4 < 4; ++k4) {
        const int off = (k4 * 64 + lq * 16) ^ swz;
        bf16x8 a = *(const bf16x8*)(XB + off);
#pragma unroll
        for (int cf = 0; cf < 8; ++cf) {
            bf16x8 b = *(const bf16x8*)(WB + cf * 4096 + off);
            acc[cf] = __builtin_amdgcn_mfma_f32_16x16x32_bf16(a, b, acc[cf], 0, 0, 0);
        }
    }
#pragma unroll
    for (int r = 0; r < 4; ++r) {
        int grow = r0g + w * 16 + lq * 4 + r;
        if (grow < n) {
            uint4 o;
            o.x = pack2bf(acc[0][r], acc[1][r]);
            o.y = pack2bf(acc[2][r], acc[3][r]);
            o.z = pack2bf(acc[4][r], acc[5][r]);
            o.w = pack2bf(acc[6][r], acc[7][r]);
            *(uint4*)((unsigned short*)Yb + (size_t)grow * 128 + lr * 8) = o;
        }
    }
}

// ---------------- attention logits from permuted bf16 Yb ----------------
// storage j = ch4*8 + e  <->  channel col = e*16 + ch4; head = e>>1 (H=4).
template <int H>
__global__ void att_from_yb(const unsigned int* __restrict__ Yb,
                            const float* __restrict__ att_s,
                            const float* __restrict__ att_d,
                            float* __restrict__ as_, float* __restrict__ ad_, int n) {
    int node = blockIdx.x * blockDim.x + threadIdx.x;
    if (node >= n) return;
    const uint4* row = (const uint4*)(Yb + (size_t)node * 64);
    float sa[H], da[H];
#pragma unroll
    for (int h = 0; h < H; ++h) { sa[h] = 0.f; da[h] = 0.f; }
#pragma unroll 4
    for (int ch4 = 0; ch4 < 16; ++ch4) {
        uint4 v = row[ch4];
#define DOPAIR(word, e0)                                                     \
        {                                                                    \
            float f0 = bf_lo(word), f1 = bf_hi(word);                        \
            const int col0 = (e0) * 16 + ch4, col1 = col0 + 16;              \
            const int h0 = (H == 4) ? ((e0) >> 1) : 0;                       \
            sa[h0] += f0 * att_s[col0] + f1 * att_s[col1];                   \
            da[h0] += f0 * att_d[col0] + f1 * att_d[col1];                   \
        }
        DOPAIR(v.x, 0) DOPAIR(v.y, 2) DOPAIR(v.z, 4) DOPAIR(v.w, 6)
#undef DOPAIR
    }
#pragma unroll
    for (int h = 0; h < H; ++h) {
        as_[(size_t)node * H + h] = sa[h];
        ad_[(size_t)node * H + h] = da[h];
    }
}

// ---------------- gather v4 on permuted Yb ----------------
// lane owns storage pair {2*lane, 2*lane+1} = channels {col0, col0+16},
// col0 = ((2*lane)&7)*16 + (lane>>2); head (H=4) = lane&3 (same for both).
template <int H, bool DO_ELU, bool OUT_BF16>
__global__ __launch_bounds__(256) void gat_gather4(
    const int* __restrict__ csr, const int* __restrict__ offs,
    const float* __restrict__ as_, const float* __restrict__ ad_,
    const unsigned int* __restrict__ hb,  // permuted bf16 pairs, 64 uints/node
    const float* __restrict__ bias, float* __restrict__ outf,
    unsigned short* __restrict__ outb, int n)
{
    constexpr int PW = (H == 4) ? 8 : 2;  // LDS words per edge {p[H], s}
    __shared__ float plds[4][64][PW];
    const int node = (int)(((size_t)blockIdx.x * blockDim.x + threadIdx.x) >> 6);
    if (node >= n) return;  // whole waves exit; kernel has no block barriers
    const int lane = threadIdx.x & 63;
    const int w = threadIdx.x >> 6;
    const int hd = lane & 3;
    const int col0 = ((2 * lane) & 7) * 16 + (lane >> 2);
    const int col1 = col0 + 16;
    const int start = offs[node];
    const int deg = offs[node + 1] - start;  // >= 1 (self-loop)

    float adx = 0.f, ady = 0.f, adz = 0.f, adw = 0.f;
    if constexpr (H == 4) {
        const float4 adv = *(const float4*)(ad_ + (size_t)node * 4);
        adx = adv.x; ady = adv.y; adz = adv.z; adw = adv.w;
    } else {
        adx = ad_[node];
    }

    float2 acc = {0.f, 0.f};
    float dsx = 0.f, dsy = 0.f, dsz = 0.f, dsw = 0.f;

    for (int base = 0; base < deg; base += 64) {
        const int cnt = min(deg - base, 64);
        if (lane < cnt) {
            const int s = csr[start + base + lane];
            const float sf = __int_as_float(s);
            if constexpr (H == 4) {
                const float4 a = ((const float4*)as_)[s];
                float e0 = a.x + adx; e0 = fmaxf(e0, NEG_SLOPE * e0);
                float e1 = a.y + ady; e1 = fmaxf(e1, NEG_SLOPE * e1);
                float e2 = a.z + adz; e2 = fmaxf(e2, NEG_SLOPE * e2);
                float e3 = a.w + adw; e3 = fmaxf(e3, NEG_SLOPE * e3);
                float4 p4 = {__expf(e0), __expf(e1), __expf(e2), __expf(e3)};
                dsx += p4.x; dsy += p4.y; dsz += p4.z; dsw += p4.w;
                *(float4*)&plds[w][lane][0] = p4;
                float4 s4 = {sf, sf, sf, sf};
                *(float4*)&plds[w][lane][4] = s4;
            } else {
                float e0 = as_[s] + adx; e0 = fmaxf(e0, NEG_SLOPE * e0);
                float p = __expf(e0);
                dsx += p;
                float2 ps = {p, sf};
                *(float2*)&plds[w][lane][0] = ps;
            }
        }
        asm volatile("s_waitcnt lgkmcnt(0)" ::: "memory");
        __builtin_amdgcn_sched_barrier(0);

        float pA = 0.f, pB = 0.f, pC = 0.f;
        unsigned int hA = 0, hB = 0, hC = 0;
#define PRELB(S, T)                                                             \
    if ((T) < cnt) {                                                            \
        const float* q = &plds[w][(T)][0];                                      \
        int _s;                                                                 \
        if constexpr (H == 4) { p##S = q[hd]; _s = __float_as_int(q[4 + hd]); } \
        else                  { p##S = q[0];  _s = __float_as_int(q[1]); }      \
        h##S = hb[(size_t)(unsigned)_s * 64 + lane];                            \
    }
#define CONSB(S)                                                                \
    {                                                                           \
        acc.x = fmaf(p##S, bf_lo(h##S), acc.x);                                 \
        acc.y = fmaf(p##S, bf_hi(h##S), acc.y);                                 \
    }
        PRELB(A, 0)
        PRELB(B, 1)
        PRELB(C, 2)
        int t = 0;
        for (; t + 3 <= cnt; t += 3) {
            CONSB(A) PRELB(A, t + 3)
            CONSB(B) PRELB(B, t + 4)
            CONSB(C) PRELB(C, t + 5)
        }
        if (t < cnt)     CONSB(A)
        if (t + 1 < cnt) CONSB(B)
        if (t + 2 < cnt) CONSB(C)
#undef PRELB
#undef CONSB
    }

#pragma unroll
    for (int o = 1; o < 64; o <<= 1) {
        dsx += __shfl_xor(dsx, o, 64);
        if constexpr (H == 4) {
            dsy += __shfl_xor(dsy, o, 64);
            dsz += __shfl_xor(dsz, o, 64);
            dsw += __shfl_xor(dsw, o, 64);
        }
    }
    float ds;
    if constexpr (H == 4) ds = hd == 0 ? dsx : hd == 1 ? dsy : hd == 2 ? dsz : dsw;
    else                  ds = dsx;

    const float bvx = bias[col0], bvy = bias[col1];
    const float inv = 1.f / (ds + 1e-16f);
    float v0 = acc.x * inv + bvx;
    float v1 = acc.y * inv + bvy;
    if constexpr (DO_ELU) {
        v0 = v0 > 0.f ? v0 : __expf(v0) - 1.f;
        v1 = v1 > 0.f ? v1 : __expf(v1) - 1.f;
    }
    if constexpr (OUT_BF16) {
        unsigned short* o16 = outb + (size_t)node * 128;
        o16[col0] = f2bf(v0);
        o16[col1] = f2bf(v1);
    } else {
        float* o32 = outf + (size_t)node * 128;
        o32[col0] = v0;
        o32[col1] = v1;
    }
}

extern "C" void kernel_launch(void* const* d_in, const int* in_sizes, int n_in,
                              void* d_out, int out_size, void* d_ws, size_t ws_size,
                              hipStream_t stream) {
    const float* x        = (const float*)d_in[0];
    const int*   ei       = (const int*)d_in[1];
    const float* W1       = (const float*)d_in[2];
    const float* att_src1 = (const float*)d_in[3];
    const float* att_dst1 = (const float*)d_in[4];
    const float* b1       = (const float*)d_in[5];
    const float* W2       = (const float*)d_in[6];
    const float* att_src2 = (const float*)d_in[7];
    const float* att_dst2 = (const float*)d_in[8];
    const float* b2       = (const float*)d_in[9];

    const int n  = in_sizes[0] / 128;
    const int E  = in_sizes[1] / 2;
    const int ET = E + n;
    const int nb = (n + 1023) / 1024;  // <= 64 for n <= 65536

    unsigned int*  ws32 = (unsigned int*)d_ws;
    unsigned int*  xb   = ws32;                          // [n*64] bf16 x
    unsigned int*  Yb   = xb + (size_t)n * 64;           // [n*64] bf16 h (permuted)
    unsigned int*  Bb   = Yb + (size_t)n * 64;           // [n*64] bf16 layer-1 out
    unsigned short* WT1 = (unsigned short*)(Bb + (size_t)n * 64);  // [128*128]
    unsigned short* WT2 = WT1 + 128 * 128;               // [128*128]
    float*         as_  = (float*)(WT2 + 128 * 128);     // [n*4]
    float*         ad_  = as_ + (size_t)n * 4;           // [n*4]
    int*           deg  = (int*)(ad_ + (size_t)n * 4);   // [n]
    int*           cur  = deg + n;                       // [n]
    int*           offs = cur + n;                       // [n+1]
    int*           bsum = offs + n + 1;                  // [64]
    int*           csr  = bsum + 64;                     // [ET]

    float* outf = (float*)d_out;

    // ---------------- CSR build ----------------
    hipMemsetAsync(deg, 0, (size_t)n * sizeof(int), stream);
    deg_hist<<<(E + 255) / 256, 256, 0, stream>>>(ei, deg, E);
    scan_part<<<nb, 256, 0, stream>>>(deg, bsum, n);
    scan_add<<<nb, 256, 0, stream>>>(deg, bsum, offs, cur, n);
    scatter_edges<<<(ET + 255) / 256, 256, 0, stream>>>(ei, offs, cur, csr, E, ET);

    // ---------------- prep ----------------
    prep_w<<<2, 256, 0, stream>>>(W1, W2, WT1, WT2);
    f32_to_bf16<<<((n * 16) + 255) / 256, 256, 0, stream>>>(x, (uint4*)xb, n * 16);

    // ---------------- layer 1 ----------------
    gemm_mfma<<<(n + 63) / 64, 256, 0, stream>>>((const unsigned short*)xb, WT1, Yb, n);
    att_from_yb<4><<<(n + 255) / 256, 256, 0, stream>>>(Yb, att_src1, att_dst1, as_, ad_, n);
    gat_gather4<4, true, true><<<((size_t)n * 64 + 255) / 256, 256, 0, stream>>>(
        csr, offs, as_, ad_, Yb, b1, nullptr, (unsigned short*)Bb, n);

    // ---------------- layer 2 ----------------
    gemm_mfma<<<(n + 63) / 64, 256, 0, stream>>>((const unsigned short*)Bb, WT2, Yb, n);
    att_from_yb<1><<<(n + 255) / 256, 256, 0, stream>>>(Yb, att_src2, att_dst2, as_, ad_, n);
    gat_gather4<1, false, false><<<((size_t)n * 64 + 255) / 256, 256, 0, stream>>>(
        csr, offs, as_, ad_, Yb, b2, outf, nullptr, n);
}

// Round 8
// 233.741 us; speedup vs baseline: 1.5356x; 1.3043x over previous
//
#include <hip/hip_runtime.h>
#include <hip/hip_bf16.h>
#include <math.h>

// GATEncoder round 8.
// - CSR build rewritten as 2-level radix partition (bucket = dst>>8):
//   P1 per-block LDS hist -> P2 cross-block scan -> P3 partition (packed
//   src|dstlow writes, bucket-grouped = write-combining friendly) -> P4
//   per-bucket CSR build with LDS counters (csr writes confined to ~17KB).
//   Kills round-7's scatter_edges (52us, 56MB write-amp) + deg_hist + scans.
// - att logits fused into MFMA GEMM epilogue (shfl_xor reduction over the
//   16-lane column group); x f32->bf16 folded into GEMM-1 staging.

#define NEG_SLOPE 0.2f
#define NBLK 256  // partition blocks (P1/P3 grid)

using bf16x8 = __attribute__((ext_vector_type(8))) short;
using f32x4  = __attribute__((ext_vector_type(4))) float;

__device__ inline unsigned short f2bf(float x) {
    union { float f; unsigned int u; } v; v.f = x;
    unsigned int b = v.u + 0x7fffu + ((v.u >> 16) & 1u);  // round-nearest-even
    return (unsigned short)(b >> 16);
}
__device__ inline unsigned int pack2bf(float a, float b) {
    return (unsigned int)f2bf(a) | ((unsigned int)f2bf(b) << 16);
}
__device__ inline float bf_lo(unsigned int u) { return __uint_as_float(u << 16); }
__device__ inline float bf_hi(unsigned int u) { return __uint_as_float(u & 0xffff0000u); }

// exclusive scan of one int per thread across a 256-thread block.
// scratch4: __shared__ int[4]. All 256 threads must call.
__device__ inline int excl_scan_256(int v, int* scratch4) {
    const int t = threadIdx.x, lane = t & 63, w = t >> 6;
    int incl = v;
#pragma unroll
    for (int o = 1; o < 64; o <<= 1) {
        int u = __shfl_up(incl, o, 64);
        if (lane >= o) incl += u;
    }
    if (lane == 63) scratch4[w] = incl;
    __syncthreads();
    int wb = 0;
#pragma unroll
    for (int k = 0; k < 4; ++k)
        if (k < w) wb += scratch4[k];
    __syncthreads();  // allow scratch reuse
    return wb + incl - v;
}

// ---------------- P1: per-block bucket histogram ----------------
__global__ __launch_bounds__(256) void part_hist(const int* __restrict__ ei,
                                                 int* __restrict__ hist,
                                                 int E, int NB, int epb) {
    __shared__ int h[256];
    const int t = threadIdx.x;
    h[t] = 0;
    __syncthreads();
    const int e0 = blockIdx.x * epb;
    const int e1 = min(e0 + epb, E);
    for (int e = e0 + t; e < e1; e += 256) atomicAdd(&h[ei[E + e] >> 8], 1);
    __syncthreads();
    if (t < NB) hist[t * NBLK + blockIdx.x] = h[t];
}

// ---------------- P2: per-bucket exclusive scan across blocks ----------------
__global__ __launch_bounds__(256) void part_scan(int* __restrict__ hist,
                                                 int* __restrict__ btotal) {
    __shared__ int s4[4];
    const int b = blockIdx.x, t = threadIdx.x;
    const int v = hist[b * NBLK + t];
    const int ex = excl_scan_256(v, s4);
    hist[b * NBLK + t] = ex;
    if (t == 255) btotal[b] = ex + v;
}

// ---------------- P3: partition edges into bucket-grouped part[] -------------
// part entry: src (bits 0..15, n < 65536) | (dst & 255) << 16.
__global__ __launch_bounds__(256) void part_scatter(const int* __restrict__ ei,
                                                    const int* __restrict__ hist,
                                                    const int* __restrict__ btotal,
                                                    unsigned int* __restrict__ part,
                                                    int E, int NB, int epb) {
    __shared__ int s4[4];
    __shared__ int cur[256];
    const int t = threadIdx.x;
    const int tv = (t < NB) ? btotal[t] : 0;
    const int pb = excl_scan_256(tv, s4);
    cur[t] = (t < NB) ? pb + hist[t * NBLK + blockIdx.x] : 0;
    __syncthreads();
    const int e0 = blockIdx.x * epb;
    const int e1 = min(e0 + epb, E);
    for (int e = e0 + t; e < e1; e += 256) {
        const int d = ei[E + e];
        const int s = ei[e];
        const int pos = atomicAdd(&cur[d >> 8], 1);
        part[pos] = (unsigned int)s | ((unsigned int)(d & 255) << 16);
    }
}

// ---------------- P4: per-bucket CSR build (LDS counters) ----------------
__global__ __launch_bounds__(256) void csr_build(const unsigned int* __restrict__ part,
                                                 const int* __restrict__ btotal,
                                                 int* __restrict__ offs,
                                                 int* __restrict__ csr,
                                                 int n, int NB, int E) {
    __shared__ int s4[4];
    __shared__ int cnt[256], curq[256];
    __shared__ int sPB, sPE, sCB;
    const int b = blockIdx.x, t = threadIdx.x;
    const int tv = (t < NB) ? btotal[t] : 0;
    const int nnt = (t < NB) ? max(0, min(256, n - t * 256)) : 0;
    const int e1 = excl_scan_256(tv, s4);        // part base of bucket t
    const int e2 = excl_scan_256(tv + nnt, s4);  // csr base (edges + self-loops)
    if (t == b) { sPB = e1; sPE = e1 + tv; sCB = e2; }
    const int node = b * 256 + t;
    cnt[t] = (node < n) ? 1 : 0;  // self-loop seed
    __syncthreads();
    for (int i = sPB + t; i < sPE; i += 256) atomicAdd(&cnt[(part[i] >> 16) & 255], 1);
    __syncthreads();
    const int c = cnt[t];
    const int loc = excl_scan_256(c, s4);
    curq[t] = loc + ((node < n) ? 1 : 0);
    if (node < n) {
        offs[node] = sCB + loc;
        csr[sCB + loc] = node;  // self-loop first
    }
    if (b == 0 && t == 0) offs[n] = E + n;
    __syncthreads();
    for (int i = sPB + t; i < sPE; i += 256) {
        const unsigned int u = part[i];
        const int pos = atomicAdd(&curq[(u >> 16) & 255], 1);
        csr[sCB + pos] = (int)(u & 0xffffu);
    }
}

// ---------------- prep: W[k][c] f32 -> WT[c][k] bf16 (both layers) ----------
__global__ __launch_bounds__(256) void prep_w(const float* __restrict__ W1,
                                              const float* __restrict__ W2,
                                              unsigned short* __restrict__ WT1,
                                              unsigned short* __restrict__ WT2) {
    const float* W = blockIdx.x ? W2 : W1;
    unsigned short* WT = blockIdx.x ? WT2 : WT1;
    __shared__ float Wl[64][132];
    const int tid = threadIdx.x;
    for (int p = 0; p < 2; ++p) {
        if (p) __syncthreads();
        for (int u = tid; u < 2048; u += 256) {  // 64 rows x 32 float4
            int row = u >> 5, ch = u & 31;
            float4 v = *(const float4*)(W + (size_t)(p * 64 + row) * 128 + ch * 4);
            Wl[row][ch * 4 + 0] = v.x; Wl[row][ch * 4 + 1] = v.y;
            Wl[row][ch * 4 + 2] = v.z; Wl[row][ch * 4 + 3] = v.w;
        }
        __syncthreads();
        for (int u = tid; u < 2048; u += 256) {  // 128 c x 16 kc (4 k each)
            int c = u >> 4, kc = u & 15;
            uint2 o;
            o.x = pack2bf(Wl[kc * 4 + 0][c], Wl[kc * 4 + 1][c]);
            o.y = pack2bf(Wl[kc * 4 + 2][c], Wl[kc * 4 + 3][c]);
            *(uint2*)(WT + (size_t)c * 128 + p * 64 + kc * 4) = o;
        }
    }
}

// ---------------- MFMA GEMM + fused attention logits ----------------
// block 256 thr = 4 waves, tile 64 rows x 128 cols, K=128 in one LDS stage.
// wave w: rows [w*16, w*16+16). C-frag: col = lane&15, row = (lane>>4)*4 + r.
// LDS XOR-swizzle: byte_in_row ^= ((row&7)<<4). Output Yb permuted:
// storage j = (l&15)*8 + cf  <->  channel col = cf*16 + (l&15).
// Epilogue: as_/ad_ = per-head dots vs att_s/att_d, reduced with shfl_xor
// over the 16-lane column group (fuses away the separate att kernel).
template <int H, bool IN_F32>
__global__ __launch_bounds__(256) void gemm_att(const float* __restrict__ Xf,
                                                const unsigned short* __restrict__ Xb,
                                                const unsigned short* __restrict__ WTb,
                                                unsigned int* __restrict__ Yb,
                                                const float* __restrict__ att_s,
                                                const float* __restrict__ att_d,
                                                float* __restrict__ as_,
                                                float* __restrict__ ad_, int n) {
    __shared__ unsigned short XL[64 * 128];
    __shared__ unsigned short WL[128 * 128];
    const int tid = threadIdx.x;
    const int r0g = blockIdx.x * 64;
#pragma unroll
    for (int p = 0; p < 4; ++p) {  // stage X tile (swizzled), converting if f32
        int u = tid + 256 * p;     // 64 rows x 16 chunks of 8 ch
        int row = u >> 4, ch = u & 15;
        uint4 v = {0, 0, 0, 0};
        int gr = r0g + row;
        if (gr < n) {
            if constexpr (IN_F32) {
                const float4* xp = (const float4*)(Xf + (size_t)gr * 128 + ch * 8);
                float4 f0 = xp[0], f1 = xp[1];
                v.x = pack2bf(f0.x, f0.y); v.y = pack2bf(f0.z, f0.w);
                v.z = pack2bf(f1.x, f1.y); v.w = pack2bf(f1.z, f1.w);
            } else {
                v = *(const uint4*)(Xb + (size_t)gr * 128 + ch * 8);
            }
        }
        int byte = (ch * 16) ^ ((row & 7) << 4);
        *(uint4*)((char*)XL + row * 256 + byte) = v;
    }
#pragma unroll
    for (int p = 0; p < 8; ++p) {  // stage WT (swizzled)
        int u = tid + 256 * p;     // 128 c x 16 chunks
        int c = u >> 4, ch = u & 15;
        uint4 v = *(const uint4*)(WTb + (size_t)c * 128 + ch * 8);
        int byte = (ch * 16) ^ ((c & 7) << 4);
        *(uint4*)((char*)WL + c * 256 + byte) = v;
    }
    __syncthreads();

    const int w = tid >> 6, lane = tid & 63;
    const int lr = lane & 15, lq = lane >> 4;
    const int swz = (lr & 7) << 4;
    f32x4 acc[8];
#pragma unroll
    for (int cf = 0; cf < 8; ++cf) acc[cf] = (f32x4){0.f, 0.f, 0.f, 0.f};

    const char* XB = (const char*)XL + (w * 16 + lr) * 256;
    const char* WB = (const char*)WL + lr * 256;
#pragma unroll
    for (int k4 = 0; k4 < 4; ++k4) {
        const int off = (k4 * 64 + lq * 16) ^ swz;
        bf16x8 a = *(const bf16x8*)(XB + off);
#pragma unroll
        for (int cf = 0; cf < 8; ++cf) {
            bf16x8 b = *(const bf16x8*)(WB + cf * 4096 + off);
            acc[cf] = __builtin_amdgcn_mfma_f32_16x16x32_bf16(a, b, acc[cf], 0, 0, 0);
        }
    }

    // ---- Yb store (permuted layout) ----
#pragma unroll
    for (int r = 0; r < 4; ++r) {
        int grow = r0g + w * 16 + lq * 4 + r;
        if (grow < n) {
            uint4 o;
            o.x = pack2bf(acc[0][r], acc[1][r]);
            o.y = pack2bf(acc[2][r], acc[3][r]);
            o.z = pack2bf(acc[4][r], acc[5][r]);
            o.w = pack2bf(acc[6][r], acc[7][r]);
            *(uint4*)((unsigned short*)Yb + (size_t)grow * 128 + lr * 8) = o;
        }
    }

    // ---- fused attention logits ----
    if constexpr (H == 4) {
        float pa[4][4], pd[4][4];  // [head][r], compile-time indexed only
#pragma unroll
        for (int h = 0; h < 4; ++h)
#pragma unroll
            for (int r = 0; r < 4; ++r) { pa[h][r] = 0.f; pd[h][r] = 0.f; }
#pragma unroll
        for (int cf = 0; cf < 8; ++cf) {
            const float ws = att_s[cf * 16 + lr];
            const float wd = att_d[cf * 16 + lr];
            constexpr int dummy = 0; (void)dummy;
#pragma unroll
            for (int r = 0; r < 4; ++r) {
                pa[cf >> 1][r] = fmaf(acc[cf][r], ws, pa[cf >> 1][r]);
                pd[cf >> 1][r] = fmaf(acc[cf][r], wd, pd[cf >> 1][r]);
            }
        }
#pragma unroll
        for (int o = 1; o < 16; o <<= 1) {
#pragma unroll
            for (int h = 0; h < 4; ++h)
#pragma unroll
                for (int r = 0; r < 4; ++r) {
                    pa[h][r] += __shfl_xor(pa[h][r], o, 64);
                    pd[h][r] += __shfl_xor(pd[h][r], o, 64);
                }
        }
        const int h = lr & 3, r = lr >> 2;
        float va = 0.f, vd = 0.f;
#pragma unroll
        for (int hh = 0; hh < 4; ++hh)
#pragma unroll
            for (int rr = 0; rr < 4; ++rr)
                if (h == hh && r == rr) { va = pa[hh][rr]; vd = pd[hh][rr]; }
        const int node = r0g + w * 16 + lq * 4 + r;
        if (node < n) {
            as_[(size_t)node * 4 + h] = va;
            ad_[(size_t)node * 4 + h] = vd;
        }
    } else {
        float pa[4], pd[4];
#pragma unroll
        for (int r = 0; r < 4; ++r) { pa[r] = 0.f; pd[r] = 0.f; }
#pragma unroll
        for (int cf = 0; cf < 8; ++cf) {
            const float ws = att_s[cf * 16 + lr];
            const float wd = att_d[cf * 16 + lr];
#pragma unroll
            for (int r = 0; r < 4; ++r) {
                pa[r] = fmaf(acc[cf][r], ws, pa[r]);
                pd[r] = fmaf(acc[cf][r], wd, pd[r]);
            }
        }
#pragma unroll
        for (int o = 1; o < 16; o <<= 1) {
#pragma unroll
            for (int r = 0; r < 4; ++r) {
                pa[r] += __shfl_xor(pa[r], o, 64);
                pd[r] += __shfl_xor(pd[r], o, 64);
            }
        }
        const int r = lr & 3;
        float va = 0.f, vd = 0.f;
#pragma unroll
        for (int rr = 0; rr < 4; ++rr)
            if (r == rr) { va = pa[rr]; vd = pd[rr]; }
        const int node = r0g + w * 16 + lq * 4 + r;
        if (node < n && lr < 8) {
            if (lr < 4) as_[node] = va;
            else        ad_[node] = vd;
        }
    }
}

// ---------------- gather v4 on permuted Yb (unchanged from round 7) ---------
template <int H, bool DO_ELU, bool OUT_BF16>
__global__ __launch_bounds__(256) void gat_gather4(
    const int* __restrict__ csr, const int* __restrict__ offs,
    const float* __restrict__ as_, const float* __restrict__ ad_,
    const unsigned int* __restrict__ hb,  // permuted bf16 pairs, 64 uints/node
    const float* __restrict__ bias, float* __restrict__ outf,
    unsigned short* __restrict__ outb, int n)
{
    constexpr int PW = (H == 4) ? 8 : 2;  // LDS words per edge {p[H], s}
    __shared__ float plds[4][64][PW];
    const int node = (int)(((size_t)blockIdx.x * blockDim.x + threadIdx.x) >> 6);
    if (node >= n) return;  // whole waves exit; kernel has no block barriers
    const int lane = threadIdx.x & 63;
    const int w = threadIdx.x >> 6;
    const int hd = lane & 3;
    const int col0 = ((2 * lane) & 7) * 16 + (lane >> 2);
    const int col1 = col0 + 16;
    const int start = offs[node];
    const int deg = offs[node + 1] - start;  // >= 1 (self-loop)

    float adx = 0.f, ady = 0.f, adz = 0.f, adw = 0.f;
    if constexpr (H == 4) {
        const float4 adv = *(const float4*)(ad_ + (size_t)node * 4);
        adx = adv.x; ady = adv.y; adz = adv.z; adw = adv.w;
    } else {
        adx = ad_[node];
    }

    float2 acc = {0.f, 0.f};
    float dsx = 0.f, dsy = 0.f, dsz = 0.f, dsw = 0.f;

    for (int base = 0; base < deg; base += 64) {
        const int cnt = min(deg - base, 64);
        if (lane < cnt) {
            const int s = csr[start + base + lane];
            const float sf = __int_as_float(s);
            if constexpr (H == 4) {
                const float4 a = ((const float4*)as_)[s];
                float e0 = a.x + adx; e0 = fmaxf(e0, NEG_SLOPE * e0);
                float e1 = a.y + ady; e1 = fmaxf(e1, NEG_SLOPE * e1);
                float e2 = a.z + adz; e2 = fmaxf(e2, NEG_SLOPE * e2);
                float e3 = a.w + adw; e3 = fmaxf(e3, NEG_SLOPE * e3);
                float4 p4 = {__expf(e0), __expf(e1), __expf(e2), __expf(e3)};
                dsx += p4.x; dsy += p4.y; dsz += p4.z; dsw += p4.w;
                *(float4*)&plds[w][lane][0] = p4;
                float4 s4 = {sf, sf, sf, sf};
                *(float4*)&plds[w][lane][4] = s4;
            } else {
                float e0 = as_[s] + adx; e0 = fmaxf(e0, NEG_SLOPE * e0);
                float p = __expf(e0);
                dsx += p;
                float2 ps = {p, sf};
                *(float2*)&plds[w][lane][0] = ps;
            }
        }
        asm volatile("s_waitcnt lgkmcnt(0)" ::: "memory");
        __builtin_amdgcn_sched_barrier(0);

        float pA = 0.f, pB = 0.f, pC = 0.f;
        unsigned int hA = 0, hB = 0, hC = 0;
#define PRELB(S, T)                                                             \
    if ((T) < cnt) {                                                            \
        const float* q = &plds[w][(T)][0];                                      \
        int _s;                                                                 \
        if constexpr (H == 4) { p##S = q[hd]; _s = __float_as_int(q[4 + hd]); } \
        else                  { p##S = q[0];  _s = __float_as_int(q[1]); }      \
        h##S = hb[(size_t)(unsigned)_s * 64 + lane];                            \
    }
#define CONSB(S)                                                                \
    {                                                                           \
        acc.x = fmaf(p##S, bf_lo(h##S), acc.x);                                 \
        acc.y = fmaf(p##S, bf_hi(h##S), acc.y);                                 \
    }
        PRELB(A, 0)
        PRELB(B, 1)
        PRELB(C, 2)
        int t = 0;
        for (; t + 3 <= cnt; t += 3) {
            CONSB(A) PRELB(A, t + 3)
            CONSB(B) PRELB(B, t + 4)
            CONSB(C) PRELB(C, t + 5)
        }
        if (t < cnt)     CONSB(A)
        if (t + 1 < cnt) CONSB(B)
        if (t + 2 < cnt) CONSB(C)
#undef PRELB
#undef CONSB
    }

#pragma unroll
    for (int o = 1; o < 64; o <<= 1) {
        dsx += __shfl_xor(dsx, o, 64);
        if constexpr (H == 4) {
            dsy += __shfl_xor(dsy, o, 64);
            dsz += __shfl_xor(dsz, o, 64);
            dsw += __shfl_xor(dsw, o, 64);
        }
    }
    float ds;
    if constexpr (H == 4) ds = hd == 0 ? dsx : hd == 1 ? dsy : hd == 2 ? dsz : dsw;
    else                  ds = dsx;

    const float bvx = bias[col0], bvy = bias[col1];
    const float inv = 1.f / (ds + 1e-16f);
    float v0 = acc.x * inv + bvx;
    float v1 = acc.y * inv + bvy;
    if constexpr (DO_ELU) {
        v0 = v0 > 0.f ? v0 : __expf(v0) - 1.f;
        v1 = v1 > 0.f ? v1 : __expf(v1) - 1.f;
    }
    if constexpr (OUT_BF16) {
        unsigned short* o16 = outb + (size_t)node * 128;
        o16[col0] = f2bf(v0);
        o16[col1] = f2bf(v1);
    } else {
        float* o32 = outf + (size_t)node * 128;
        o32[col0] = v0;
        o32[col1] = v1;
    }
}

extern "C" void kernel_launch(void* const* d_in, const int* in_sizes, int n_in,
                              void* d_out, int out_size, void* d_ws, size_t ws_size,
                              hipStream_t stream) {
    const float* x        = (const float*)d_in[0];
    const int*   ei       = (const int*)d_in[1];
    const float* W1       = (const float*)d_in[2];
    const float* att_src1 = (const float*)d_in[3];
    const float* att_dst1 = (const float*)d_in[4];
    const float* b1       = (const float*)d_in[5];
    const float* W2       = (const float*)d_in[6];
    const float* att_src2 = (const float*)d_in[7];
    const float* att_dst2 = (const float*)d_in[8];
    const float* b2       = (const float*)d_in[9];

    const int n  = in_sizes[0] / 128;
    const int E  = in_sizes[1] / 2;
    const int ET = E + n;
    const int NB = (n + 255) >> 8;           // dst buckets (196 for n=50000)
    const int epb = (E + NBLK - 1) / NBLK;   // edges per partition block

    unsigned int*   ws32 = (unsigned int*)d_ws;
    unsigned int*   Yb   = ws32;                                   // [n*64]
    unsigned int*   Bb   = Yb + (size_t)n * 64;                    // [n*64]
    unsigned short* WT1  = (unsigned short*)(Bb + (size_t)n * 64); // [128*128]
    unsigned short* WT2  = WT1 + 128 * 128;                        // [128*128]
    float*          as_  = (float*)(WT2 + 128 * 128);              // [n*4]
    float*          ad_  = as_ + (size_t)n * 4;                    // [n*4]
    int*            offs = (int*)(ad_ + (size_t)n * 4);            // [n+1]
    int*            csr  = offs + n + 1;                           // [ET]
    unsigned int*   part = (unsigned int*)(csr + ET);              // [E]
    int*            hist = (int*)(part + E);                       // [NB*NBLK]
    int*            btot = hist + (size_t)NB * NBLK;               // [NB]

    float* outf = (float*)d_out;

    // ---------------- CSR build (radix partition) ----------------
    part_hist<<<NBLK, 256, 0, stream>>>(ei, hist, E, NB, epb);
    part_scan<<<NB, 256, 0, stream>>>(hist, btot);
    part_scatter<<<NBLK, 256, 0, stream>>>(ei, hist, btot, part, E, NB, epb);
    csr_build<<<NB, 256, 0, stream>>>(part, btot, offs, csr, n, NB, E);

    // ---------------- prep ----------------
    prep_w<<<2, 256, 0, stream>>>(W1, W2, WT1, WT2);

    // ---------------- layer 1 ----------------
    gemm_att<4, true><<<(n + 63) / 64, 256, 0, stream>>>(
        x, nullptr, WT1, Yb, att_src1, att_dst1, as_, ad_, n);
    gat_gather4<4, true, true><<<((size_t)n * 64 + 255) / 256, 256, 0, stream>>>(
        csr, offs, as_, ad_, Yb, b1, nullptr, (unsigned short*)Bb, n);

    // ---------------- layer 2 ----------------
    gemm_att<1, false><<<(n + 63) / 64, 256, 0, stream>>>(
        nullptr, (const unsigned short*)Bb, WT2, Yb, att_src2, att_dst2, as_, ad_, n);
    gat_gather4<1, false, false><<<((size_t)n * 64 + 255) / 256, 256, 0, stream>>>(
        csr, offs, as_, ad_, Yb, b2, outf, nullptr, n);
}